// Round 6
// baseline (258.365 us; speedup 1.0000x reference)
//
#include <hip/hip_runtime.h>

// Attention_86423331930517 — MI355X bf16-MFMA implementation, round 6.
// B=16, H=W=64, C=512, HW=4096, P=1024 pooled pixels, D=64 (qk dim), DV=256 (v dim).
// Round-6 changes: out-projection UN-fused (fused epilogue measured ~90us due to zero
// register slack at 244 regs -> serial load latency). attn writes y bf16 again; new
// single-stage streaming gemm_out (y staged once via global_load_lds + 32-slot XOR
// swizzle, no K-loop, 2-deep x prefetch, split mfma chains). f pre-scaled by log2e
// in its GEMM so attn softmax uses raw v_exp_f32 (exp2f).

#define DEVI static __device__ __forceinline__

typedef float f32x4  __attribute__((ext_vector_type(4)));
typedef float f32x16 __attribute__((ext_vector_type(16)));
typedef short bf16x8 __attribute__((ext_vector_type(8)));

DEVI short f2bf(float f) {
  union { float f; unsigned u; } v; v.f = f;
  unsigned r = v.u + 0x7FFFu + ((v.u >> 16) & 1u);   // RNE
  return (short)(r >> 16);
}
DEVI float b2f(short s) {
  union { unsigned u; float f; } v; v.u = ((unsigned)(unsigned short)s) << 16; return v.f;
}
DEVI unsigned cvtpk(float lo, float hi) {        // dst = {bf16(lo) | bf16(hi)<<16}, RNE
  unsigned r;
  asm("v_cvt_pk_bf16_f32 %0, %1, %2" : "=v"(r) : "v"(lo), "v"(hi));
  return r;
}
DEVI f32x4 mfma16(bf16x8 a, bf16x8 b, f32x4 c) {
  return __builtin_amdgcn_mfma_f32_16x16x32_bf16(a, b, c, 0, 0, 0);
}
DEVI f32x16 mfma32(bf16x8 a, bf16x8 b, f32x16 c) {
  return __builtin_amdgcn_mfma_f32_32x32x16_bf16(a, b, c, 0, 0, 0);
}
DEVI void gload16(const short* gsrc, short* lds) {
  __builtin_amdgcn_global_load_lds(
      (const __attribute__((address_space(1))) void*)gsrc,
      (__attribute__((address_space(3))) void*)lds, 16, 0, 0);
}

// ---------------- weights: cast to bf16 and transpose so B-operand rows are k-contiguous
__global__ __launch_bounds__(256) void prep_weights(
    const float* __restrict__ Wf, const float* __restrict__ Wg,
    const float* __restrict__ Wh, const float* __restrict__ Wo,
    short* __restrict__ WfT, short* __restrict__ WgT,
    short* __restrict__ WhT, short* __restrict__ WoT) {
  int i = blockIdx.x * 256 + threadIdx.x;   // 0..393215 exactly
  const float* src; short* dst; int K, N, e;
  if (i < 32768)       { src = Wf; dst = WfT; K = 512; N = 64;  e = i; }
  else if (i < 65536)  { src = Wg; dst = WgT; K = 512; N = 64;  e = i - 32768; }
  else if (i < 196608) { src = Wh; dst = WhT; K = 512; N = 256; e = i - 65536; }
  else                 { src = Wo; dst = WoT; K = 256; N = 512; e = i - 196608; }
  int n = e / K, k = e - n * K;            // dst[n][k] = src[k][n]
  dst[e] = f2bf(src[(long)k * N + n]);
}

// ---------------- staging helper: tile of `rows` x 64 bf16 into XOR-swizzled LDS -------
template<bool SRC_F32>
DEVI void stage64(short* lds, const void* gsrc, int rows, int stride, int tid) {
  const int chunks = rows * 8;
  for (int c = tid; c < chunks; c += 256) {
    int row = c >> 3, slot = c & 7;
    int dstb = row*128 + ((slot ^ (row & 7)) << 4);
    if (SRC_F32) {
      const float* s = (const float*)gsrc + (long)row*stride + slot*8;
      float4 u0 = *(const float4*)s;
      float4 u1 = *(const float4*)(s + 4);
      union { unsigned u[4]; bf16x8 v; } pk;
      pk.u[0] = cvtpk(u0.x, u0.y); pk.u[1] = cvtpk(u0.z, u0.w);
      pk.u[2] = cvtpk(u1.x, u1.y); pk.u[3] = cvtpk(u1.z, u1.w);
      *(bf16x8*)((char*)lds + dstb) = pk.v;
    } else {
      *(bf16x8*)((char*)lds + dstb) =
          *(const bf16x8*)((const short*)gsrc + (long)row*stride + slot*8);
    }
  }
}

// ---------------- generic K=512 GEMM: C[M,Nfull] = A[M,512] @ BT[N,512]^T (bf16 out) ---
// cscale: applied at C-write (f-GEMM uses log2(e) so attn can use raw exp2).
template<bool A_F32, bool POOL>
__global__ __launch_bounds__(256) void gemm_k512(const void* __restrict__ A,
    const short* __restrict__ BT, short* __restrict__ C, int Nfull,
    short* __restrict__ xp, float cscale) {
  __shared__ short As[128*64];
  __shared__ short Bs[64*64];
  const int m0 = blockIdx.x * 128;
  const int n0 = blockIdx.y * 64;
  const int tid = threadIdx.x, w = tid >> 6, lane = tid & 63;
  const int l15 = lane & 15, lhi = lane >> 4;
  const int wr = w >> 1, wc = w & 1;
  f32x4 acc[4][2] = {};
  for (int kt = 0; kt < 8; ++kt) {
    const int k0 = kt * 64;
    if constexpr (A_F32)
      stage64<true >(As, (const float*)A + (long)m0*512 + k0, 128, 512, tid);
    else
      stage64<false>(As, (const short*)A + (long)m0*512 + k0, 128, 512, tid);
    stage64<false>(Bs, BT + (long)n0*512 + k0, 64, 512, tid);
    __syncthreads();
    if constexpr (POOL) {
      const long pr0 = (long)(m0 >> 12)*1024 + ((m0 & 4095) >> 7)*32;
      int wp = tid >> 3, cs = tid & 7;
      const char* Ab = (const char*)As;
      bf16x8 v00 = *(const bf16x8*)(Ab + (2*wp  )*128 + ((cs ^ ((2*wp  )&7))<<4));
      bf16x8 v01 = *(const bf16x8*)(Ab + (2*wp+1)*128 + ((cs ^ ((2*wp+1)&7))<<4));
      bf16x8 v10 = *(const bf16x8*)(Ab + (64+2*wp)*128 + ((cs ^ ((2*wp  )&7))<<4));
      bf16x8 v11 = *(const bf16x8*)(Ab + (65+2*wp)*128 + ((cs ^ ((2*wp+1)&7))<<4));
      float s[8];
      #pragma unroll
      for (int j = 0; j < 8; ++j)
        s[j] = 0.25f*(b2f(v00[j])+b2f(v01[j])+b2f(v10[j])+b2f(v11[j]));
      union { unsigned u[4]; bf16x8 v; } pk;
      pk.u[0] = cvtpk(s[0], s[1]); pk.u[1] = cvtpk(s[2], s[3]);
      pk.u[2] = cvtpk(s[4], s[5]); pk.u[3] = cvtpk(s[6], s[7]);
      *(bf16x8*)(xp + (pr0 + wp)*512 + k0 + cs*8) = pk.v;
    }
    bf16x8 af[4][2], bfr[2][2];
    #pragma unroll
    for (int mi = 0; mi < 4; ++mi)
      #pragma unroll
      for (int ks = 0; ks < 2; ++ks) {
        int m = wr*64 + mi*16 + l15;
        int slot = lhi + ks*4;
        af[mi][ks] = *(const bf16x8*)((const char*)As + m*128 + ((slot ^ (m & 7)) << 4));
      }
    #pragma unroll
    for (int ni = 0; ni < 2; ++ni)
      #pragma unroll
      for (int ks = 0; ks < 2; ++ks) {
        int n = wc*32 + ni*16 + l15;
        int slot = lhi + ks*4;
        bfr[ni][ks] = *(const bf16x8*)((const char*)Bs + n*128 + ((slot ^ (n & 7)) << 4));
      }
    #pragma unroll
    for (int ks = 0; ks < 2; ++ks)
      #pragma unroll
      for (int mi = 0; mi < 4; ++mi)
        #pragma unroll
        for (int ni = 0; ni < 2; ++ni)
          acc[mi][ni] = mfma16(af[mi][ks], bfr[ni][ks], acc[mi][ni]);
    __syncthreads();
  }
  #pragma unroll
  for (int mi = 0; mi < 4; ++mi)
    #pragma unroll
    for (int ni = 0; ni < 2; ++ni)
      #pragma unroll
      for (int r = 0; r < 4; ++r) {
        long row = m0 + wr*64 + mi*16 + lhi*4 + r;
        int col = n0 + wc*32 + ni*16 + l15;
        C[row * (long)Nfull + col] = f2bf(acc[mi][ni][r] * cscale);
      }
}

// ---------------- h[16*1024,256] -> hT[16*256,1024] (bf16 transpose) -------------------
__global__ __launch_bounds__(256) void transpose_h(const short* __restrict__ h,
                                                   short* __restrict__ hT) {
  __shared__ short t[64][72];
  const int k0 = blockIdx.x * 64, n0 = blockIdx.y * 64, b = blockIdx.z;
  const int tid = threadIdx.x;
  {
    int row = tid >> 2, cch = (tid & 3) * 16;
    const short* src = h + ((long)b*1024 + k0 + row) * 256 + n0 + cch;
    *(bf16x8*)&t[row][cch]     = *(const bf16x8*)src;
    *(bf16x8*)&t[row][cch + 8] = *(const bf16x8*)(src + 8);
  }
  __syncthreads();
  {
    int n = tid >> 2, kch = (tid & 3) * 16;
    bf16x8 lo, hi;
    #pragma unroll
    for (int j = 0; j < 8; ++j) { lo[j] = t[kch + j][n]; hi[j] = t[kch + 8 + j][n]; }
    short* dst = hT + ((long)b*256 + n0 + n) * 1024 + k0 + kch;
    *(bf16x8*)dst       = lo;
    *(bf16x8*)(dst + 8) = hi;
  }
}

// ---------------- fused attention, 32x32x16 MFMA, QBLK=128, 4 waves, 2 blocks/CU -------
// Swapped QK^T: S = mfma(g, f) -> q=lane&31 lane-local (f pre-scaled by log2e -> raw
// exp2). P assembled IN-REGISTER via v_cvt_pk_bf16_f32 + v_permlane32_swap_b32.
// Swapped PV: y = mfma(hT, P). Counted s_waitcnt vmcnt(10) + raw barriers.
// Epilogue: normalize, assemble y^T frags, store y bf16.
__global__ __launch_bounds__(256, 2) void attn_kernel(const short* __restrict__ f,
    const short* __restrict__ g, const short* __restrict__ hT,
    short* __restrict__ y) {
  extern __shared__ __align__(16) char smem[];
  const int b = blockIdx.y, q0 = blockIdx.x * 128;
  const int tid = threadIdx.x, w = tid >> 6, lane = tid & 63;
  const int l31 = lane & 31, hi = lane >> 5;

  bf16x8 fq[4];
  {
    const short* frow = f + ((long)b*4096 + q0 + w*32 + l31) * 64;
    #pragma unroll
    for (int ks = 0; ks < 4; ++ks) fq[ks] = *(const bf16x8*)(frow + ks*16 + hi*8);
  }

  f32x16 acc2[8] = {};     // [nc2] : n = nc2*32 + (g&3)+8*(g>>2)+4*hi, q = l31
  float rsq = 0.f;

  auto stage = [&](int buf, int kt) {   // 10 gload16 per wave per call
    const int k0 = kt * 64;
    short* gbuf = (short*)(smem + buf*8192);
    short* hbuf = (short*)(smem + 16384 + buf*32768);
    #pragma unroll
    for (int it = 0; it < 2; ++it) {          // g: 64 rows x 8 slots = 512 chunks
      int c = it*256 + w*64 + lane;
      int row = c >> 3, gslot = (c & 7) ^ (row & 7);
      gload16(g + ((long)b*1024 + k0 + row)*64 + gslot*8, gbuf + (it*256 + w*64)*8);
    }
    #pragma unroll
    for (int it = 0; it < 8; ++it) {          // hT: 256 rows x 8 slots = 2048 chunks
      int c = it*256 + w*64 + lane;
      int row = c >> 3, gslot = (c & 7) ^ (row & 7);
      gload16(hT + ((long)b*256 + row)*1024 + k0 + gslot*8, hbuf + (it*256 + w*64)*8);
    }
  };

  stage(0, 0);
  int cur = 0;
  for (int kt = 0; kt < 16; ++kt) {
    if (kt < 15) {
      stage(cur ^ 1, kt + 1);
      // wait only for CURRENT tile's 10 loads (issued last iter); next's 10 stay in flight
      asm volatile("s_waitcnt vmcnt(10)" ::: "memory");
    } else {
      asm volatile("s_waitcnt vmcnt(0)" ::: "memory");
    }
    __builtin_amdgcn_s_barrier();          // current buffer visible to all waves
    const char* gcur = (const char*)(smem + cur*8192);
    const char* hcur = (const char*)(smem + 16384 + cur*32768);
    // ---- QK^T (swapped) + exp2 + in-register P^T fragment assembly ----
    bf16x8 pa[4];
    #pragma unroll
    for (int kc2 = 0; kc2 < 2; ++kc2) {
      f32x16 s2 = {};
      #pragma unroll
      for (int ks = 0; ks < 4; ++ks) {
        int key = kc2*32 + l31;
        bf16x8 gb = *(const bf16x8*)(gcur + key*128 + (((ks*2 + hi) ^ (l31 & 7)) << 4));
        s2 = mfma32(gb, fq[ks], s2);
      }
      #pragma unroll
      for (int fh = 0; fh < 2; ++fh) {
        const int G = fh*8;
        float e0 = exp2f(s2[G+0]), e1 = exp2f(s2[G+1]);
        float e2 = exp2f(s2[G+2]), e3 = exp2f(s2[G+3]);
        float e4 = exp2f(s2[G+4]), e5 = exp2f(s2[G+5]);
        float e6 = exp2f(s2[G+6]), e7 = exp2f(s2[G+7]);
        rsq += ((e0 + e1) + (e2 + e3)) + ((e4 + e5) + (e6 + e7));
        unsigned a0 = cvtpk(e0, e1), a1 = cvtpk(e2, e3);
        unsigned b0 = cvtpk(e4, e5), b1 = cvtpk(e6, e7);
        asm volatile("v_permlane32_swap_b32 %0, %1" : "+v"(b0), "+v"(a0));
        asm volatile("v_permlane32_swap_b32 %0, %1" : "+v"(b1), "+v"(a1));
        union { unsigned u[4]; bf16x8 v; } pk;
        pk.u[0] = a0; pk.u[1] = a1; pk.u[2] = b0; pk.u[3] = b1;
        pa[kc2*2 + fh] = pk.v;
      }
    }
    // ---- PV (swapped), P from registers ----
    __builtin_amdgcn_s_setprio(1);
    #pragma unroll
    for (int ks = 0; ks < 4; ++ks) {
      #pragma unroll
      for (int nc2 = 0; nc2 < 8; ++nc2) {
        int n = nc2*32 + l31;
        bf16x8 hb = *(const bf16x8*)(hcur + n*128 + (((ks*2 + hi) ^ (l31 & 7)) << 4));
        acc2[nc2] = mfma32(hb, pa[ks], acc2[nc2]);
      }
    }
    __builtin_amdgcn_s_setprio(0);
    __builtin_amdgcn_s_barrier();          // all waves done reading cur before overwrite
    cur ^= 1;
  }
  // ---- normalize + assemble y^T frags in-register + store y ----
  rsq += __shfl_xor(rsq, 32);
  float ri = 1.f / rsq;
  const long qrow = (long)b*4096 + q0 + w*32 + l31;
  short* yrow = y + qrow*256;
  #pragma unroll
  for (int nc2 = 0; nc2 < 8; ++nc2) {
    #pragma unroll
    for (int fh = 0; fh < 2; ++fh) {
      const int G = fh*8;
      unsigned a0 = cvtpk(acc2[nc2][G+0]*ri, acc2[nc2][G+1]*ri);
      unsigned a1 = cvtpk(acc2[nc2][G+2]*ri, acc2[nc2][G+3]*ri);
      unsigned b0 = cvtpk(acc2[nc2][G+4]*ri, acc2[nc2][G+5]*ri);
      unsigned b1 = cvtpk(acc2[nc2][G+6]*ri, acc2[nc2][G+7]*ri);
      asm volatile("v_permlane32_swap_b32 %0, %1" : "+v"(b0), "+v"(a0));
      asm volatile("v_permlane32_swap_b32 %0, %1" : "+v"(b1), "+v"(a1));
      union { unsigned u[4]; bf16x8 v; } pk;
      pk.u[0] = a0; pk.u[1] = a1; pk.u[2] = b0; pk.u[3] = b1;
      *(bf16x8*)(yrow + (nc2*2 + fh)*16 + hi*8) = pk.v;
    }
  }
}

// ---------------- out = y[65536,256] @ WoT[512,256]^T + x (f32 out), streaming ---------
// Single-stage: whole 128x256 y-tile staged ONCE via global_load_lds with full 32-slot
// XOR swizzle (rows are 512B = 32 slots of 16B -> conflict-light reads), ONE barrier,
// all 16 y^T fragments preloaded to registers, then 16 independent cc2 iterations:
// 16 WoT L2-loads (compiler-staggered waits) + 2x8 split mfma chains + 2-deep x
// prefetch + fire-and-forget float4 stores. No K-loop, no further barriers.
__global__ __launch_bounds__(256) void gemm_out(const short* __restrict__ y,
    const short* __restrict__ WoT, const float* __restrict__ x,
    float* __restrict__ out) {
  __shared__ short ys[128*256];   // 64 KB
  const int q0 = blockIdx.x * 128;
  const int tid = threadIdx.x, w = tid >> 6, lane = tid & 63;
  const int l31 = lane & 31, hi = lane >> 5;
  // stage y: 4096 chunks of 16B; linear dest chunk c holds source slot (c&31)^(row&31)
  #pragma unroll
  for (int it = 0; it < 16; ++it) {
    int c = it*256 + w*64 + lane;
    int row = c >> 5, gslot = (c & 31) ^ (row & 31);
    gload16(y + ((long)q0 + row)*256 + gslot*8, (short*)ys + (it*256 + w*64)*8);
  }
  asm volatile("s_waitcnt vmcnt(0)" ::: "memory");
  __builtin_amdgcn_s_barrier();
  // preload all 16 y^T B-fragments: col=q=l31, k = ks*16 + hi*8 + j
  const int qr = w*32 + l31;
  bf16x8 yB[16];
  #pragma unroll
  for (int ks = 0; ks < 16; ++ks) {
    int slot = (ks*2 + hi) ^ (qr & 31);
    yB[ks] = *(const bf16x8*)((const char*)ys + qr*512 + slot*16);
  }
  const long qrow = (long)q0 + qr;
  const float* xrow = x + qrow*512;
  float* orow = out + qrow*512;
  // 2-deep x prefetch ring
  float4 xcur[4], xnxt[4];
  #pragma unroll
  for (int g2 = 0; g2 < 4; ++g2) xcur[g2] = *(const float4*)(xrow + g2*8 + hi*4);
  #pragma unroll
  for (int g2 = 0; g2 < 4; ++g2) xnxt[g2] = *(const float4*)(xrow + 32 + g2*8 + hi*4);
  for (int cc2 = 0; cc2 < 16; ++cc2) {
    bf16x8 wo[16];
    const short* wrow = WoT + ((long)cc2*32 + l31)*256 + hi*8;
    #pragma unroll
    for (int ns = 0; ns < 16; ++ns) wo[ns] = *(const bf16x8*)(wrow + ns*16);
    f32x16 ao0 = {}, ao1 = {};
    #pragma unroll
    for (int ns2 = 0; ns2 < 8; ++ns2) {
      ao0 = mfma32(wo[2*ns2  ], yB[2*ns2  ], ao0);
      ao1 = mfma32(wo[2*ns2+1], yB[2*ns2+1], ao1);
    }
    #pragma unroll
    for (int g2 = 0; g2 < 4; ++g2) {
      int c = cc2*32 + g2*8 + hi*4;
      float4 ov;
      ov.x = ao0[g2*4+0] + ao1[g2*4+0] + xcur[g2].x;
      ov.y = ao0[g2*4+1] + ao1[g2*4+1] + xcur[g2].y;
      ov.z = ao0[g2*4+2] + ao1[g2*4+2] + xcur[g2].z;
      ov.w = ao0[g2*4+3] + ao1[g2*4+3] + xcur[g2].w;
      *(float4*)(orow + c) = ov;
    }
    #pragma unroll
    for (int g2 = 0; g2 < 4; ++g2) {
      xcur[g2] = xnxt[g2];
      if (cc2 < 14) xnxt[g2] = *(const float4*)(xrow + (cc2+2)*32 + g2*8 + hi*4);
    }
  }
}

extern "C" void kernel_launch(void* const* d_in, const int* in_sizes, int n_in,
                              void* d_out, int out_size, void* d_ws, size_t ws_size,
                              hipStream_t stream) {
  const float* x  = (const float*)d_in[0];
  const float* Wf = (const float*)d_in[1];
  const float* Wg = (const float*)d_in[2];
  const float* Wh = (const float*)d_in[3];
  const float* Wo = (const float*)d_in[4];
  float* out = (float*)d_out;

  // workspace carve-up (bf16 elements)
  short* xp  = (short*)d_ws;                    // [16*1024, 512]
  short* fb  = xp  + (long)16*1024*512;         // [65536, 64]
  short* gb  = fb  + (long)65536*64;            // [16384, 64]
  short* hb  = gb  + (long)16384*64;            // [16384, 256]
  short* hTb = hb  + (long)16384*256;           // [16*256, 1024]
  short* yb  = hTb + (long)16*256*1024;         // [65536, 256]
  short* WfT = yb  + (long)65536*256;           // [64, 512]
  short* WgT = WfT + 64*512;
  short* WhT = WgT + 64*512;
  short* WoT = WhT + 256*512;

  hipFuncSetAttribute((const void*)attn_kernel,
                      hipFuncAttributeMaxDynamicSharedMemorySize, 81920);

  const float LOG2E = 1.44269504f;
  prep_weights<<<1536, 256, 0, stream>>>(Wf, Wg, Wh, Wo, WfT, WgT, WhT, WoT);
  gemm_k512<true , true ><<<dim3(512, 1), 256, 0, stream>>>((const void*)x,  WfT, fb, 64,  xp, LOG2E);
  gemm_k512<false, false><<<dim3(128, 1), 256, 0, stream>>>((const void*)xp, WgT, gb, 64,  nullptr, 1.0f);
  gemm_k512<false, false><<<dim3(128, 4), 256, 0, stream>>>((const void*)xp, WhT, hb, 256, nullptr, 1.0f);
  transpose_h <<<dim3(16, 4, 16), 256, 0, stream>>>(hb, hTb);
  attn_kernel <<<dim3(32, 16), 256, 81920, stream>>>(fb, gb, hTb, yb);
  gemm_out    <<<512, 256, 0, stream>>>(yb, WoT, x, out);
}

// Round 7
// 211.947 us; speedup vs baseline: 1.2190x; 1.2190x over previous
//
#include <hip/hip_runtime.h>

// Attention_86423331930517 — MI355X bf16-MFMA implementation, round 7.
// B=16, H=W=64, C=512, HW=4096, P=1024 pooled pixels, D=64 (qk dim), DV=256 (v dim).
// Round-7 changes: gemm_out rebuilt with UN-swapped operand order (col=lane) so x-loads
// and out-stores are coalesced 128B segments (round-6 swapped version was 16B/lane at
// 2KB stride -> 662 GB/s). attn: y-store now goes through per-wave LDS staging for
// coalesced global writes; XCD-aware block swizzle (each XCD owns 2 whole batches ->
// K/V re-reads are XCD-L2-local).

#define DEVI static __device__ __forceinline__

typedef float f32x4  __attribute__((ext_vector_type(4)));
typedef float f32x16 __attribute__((ext_vector_type(16)));
typedef short bf16x8 __attribute__((ext_vector_type(8)));

DEVI short f2bf(float f) {
  union { float f; unsigned u; } v; v.f = f;
  unsigned r = v.u + 0x7FFFu + ((v.u >> 16) & 1u);   // RNE
  return (short)(r >> 16);
}
DEVI float b2f(short s) {
  union { unsigned u; float f; } v; v.u = ((unsigned)(unsigned short)s) << 16; return v.f;
}
DEVI unsigned cvtpk(float lo, float hi) {        // dst = {bf16(lo) | bf16(hi)<<16}, RNE
  unsigned r;
  asm("v_cvt_pk_bf16_f32 %0, %1, %2" : "=v"(r) : "v"(lo), "v"(hi));
  return r;
}
DEVI f32x4 mfma16(bf16x8 a, bf16x8 b, f32x4 c) {
  return __builtin_amdgcn_mfma_f32_16x16x32_bf16(a, b, c, 0, 0, 0);
}
DEVI f32x16 mfma32(bf16x8 a, bf16x8 b, f32x16 c) {
  return __builtin_amdgcn_mfma_f32_32x32x16_bf16(a, b, c, 0, 0, 0);
}
DEVI void gload16(const short* gsrc, short* lds) {
  __builtin_amdgcn_global_load_lds(
      (const __attribute__((address_space(1))) void*)gsrc,
      (__attribute__((address_space(3))) void*)lds, 16, 0, 0);
}

// ---------------- weights: cast to bf16 and transpose so B-operand rows are k-contiguous
__global__ __launch_bounds__(256) void prep_weights(
    const float* __restrict__ Wf, const float* __restrict__ Wg,
    const float* __restrict__ Wh, const float* __restrict__ Wo,
    short* __restrict__ WfT, short* __restrict__ WgT,
    short* __restrict__ WhT, short* __restrict__ WoT) {
  int i = blockIdx.x * 256 + threadIdx.x;   // 0..393215 exactly
  const float* src; short* dst; int K, N, e;
  if (i < 32768)       { src = Wf; dst = WfT; K = 512; N = 64;  e = i; }
  else if (i < 65536)  { src = Wg; dst = WgT; K = 512; N = 64;  e = i - 32768; }
  else if (i < 196608) { src = Wh; dst = WhT; K = 512; N = 256; e = i - 65536; }
  else                 { src = Wo; dst = WoT; K = 256; N = 512; e = i - 196608; }
  int n = e / K, k = e - n * K;            // dst[n][k] = src[k][n]
  dst[e] = f2bf(src[(long)k * N + n]);
}

// ---------------- staging helper: tile of `rows` x 64 bf16 into XOR-swizzled LDS -------
template<bool SRC_F32>
DEVI void stage64(short* lds, const void* gsrc, int rows, int stride, int tid) {
  const int chunks = rows * 8;
  for (int c = tid; c < chunks; c += 256) {
    int row = c >> 3, slot = c & 7;
    int dstb = row*128 + ((slot ^ (row & 7)) << 4);
    if (SRC_F32) {
      const float* s = (const float*)gsrc + (long)row*stride + slot*8;
      float4 u0 = *(const float4*)s;
      float4 u1 = *(const float4*)(s + 4);
      union { unsigned u[4]; bf16x8 v; } pk;
      pk.u[0] = cvtpk(u0.x, u0.y); pk.u[1] = cvtpk(u0.z, u0.w);
      pk.u[2] = cvtpk(u1.x, u1.y); pk.u[3] = cvtpk(u1.z, u1.w);
      *(bf16x8*)((char*)lds + dstb) = pk.v;
    } else {
      *(bf16x8*)((char*)lds + dstb) =
          *(const bf16x8*)((const short*)gsrc + (long)row*stride + slot*8);
    }
  }
}

// ---------------- generic K=512 GEMM: C[M,Nfull] = A[M,512] @ BT[N,512]^T (bf16 out) ---
// cscale: applied at C-write (f-GEMM uses log2(e) so attn can use raw exp2).
template<bool A_F32, bool POOL>
__global__ __launch_bounds__(256) void gemm_k512(const void* __restrict__ A,
    const short* __restrict__ BT, short* __restrict__ C, int Nfull,
    short* __restrict__ xp, float cscale) {
  __shared__ short As[128*64];
  __shared__ short Bs[64*64];
  const int m0 = blockIdx.x * 128;
  const int n0 = blockIdx.y * 64;
  const int tid = threadIdx.x, w = tid >> 6, lane = tid & 63;
  const int l15 = lane & 15, lhi = lane >> 4;
  const int wr = w >> 1, wc = w & 1;
  f32x4 acc[4][2] = {};
  for (int kt = 0; kt < 8; ++kt) {
    const int k0 = kt * 64;
    if constexpr (A_F32)
      stage64<true >(As, (const float*)A + (long)m0*512 + k0, 128, 512, tid);
    else
      stage64<false>(As, (const short*)A + (long)m0*512 + k0, 128, 512, tid);
    stage64<false>(Bs, BT + (long)n0*512 + k0, 64, 512, tid);
    __syncthreads();
    if constexpr (POOL) {
      const long pr0 = (long)(m0 >> 12)*1024 + ((m0 & 4095) >> 7)*32;
      int wp = tid >> 3, cs = tid & 7;
      const char* Ab = (const char*)As;
      bf16x8 v00 = *(const bf16x8*)(Ab + (2*wp  )*128 + ((cs ^ ((2*wp  )&7))<<4));
      bf16x8 v01 = *(const bf16x8*)(Ab + (2*wp+1)*128 + ((cs ^ ((2*wp+1)&7))<<4));
      bf16x8 v10 = *(const bf16x8*)(Ab + (64+2*wp)*128 + ((cs ^ ((2*wp  )&7))<<4));
      bf16x8 v11 = *(const bf16x8*)(Ab + (65+2*wp)*128 + ((cs ^ ((2*wp+1)&7))<<4));
      float s[8];
      #pragma unroll
      for (int j = 0; j < 8; ++j)
        s[j] = 0.25f*(b2f(v00[j])+b2f(v01[j])+b2f(v10[j])+b2f(v11[j]));
      union { unsigned u[4]; bf16x8 v; } pk;
      pk.u[0] = cvtpk(s[0], s[1]); pk.u[1] = cvtpk(s[2], s[3]);
      pk.u[2] = cvtpk(s[4], s[5]); pk.u[3] = cvtpk(s[6], s[7]);
      *(bf16x8*)(xp + (pr0 + wp)*512 + k0 + cs*8) = pk.v;
    }
    bf16x8 af[4][2], bfr[2][2];
    #pragma unroll
    for (int mi = 0; mi < 4; ++mi)
      #pragma unroll
      for (int ks = 0; ks < 2; ++ks) {
        int m = wr*64 + mi*16 + l15;
        int slot = lhi + ks*4;
        af[mi][ks] = *(const bf16x8*)((const char*)As + m*128 + ((slot ^ (m & 7)) << 4));
      }
    #pragma unroll
    for (int ni = 0; ni < 2; ++ni)
      #pragma unroll
      for (int ks = 0; ks < 2; ++ks) {
        int n = wc*32 + ni*16 + l15;
        int slot = lhi + ks*4;
        bfr[ni][ks] = *(const bf16x8*)((const char*)Bs + n*128 + ((slot ^ (n & 7)) << 4));
      }
    #pragma unroll
    for (int ks = 0; ks < 2; ++ks)
      #pragma unroll
      for (int mi = 0; mi < 4; ++mi)
        #pragma unroll
        for (int ni = 0; ni < 2; ++ni)
          acc[mi][ni] = mfma16(af[mi][ks], bfr[ni][ks], acc[mi][ni]);
    __syncthreads();
  }
  #pragma unroll
  for (int mi = 0; mi < 4; ++mi)
    #pragma unroll
    for (int ni = 0; ni < 2; ++ni)
      #pragma unroll
      for (int r = 0; r < 4; ++r) {
        long row = m0 + wr*64 + mi*16 + lhi*4 + r;
        int col = n0 + wc*32 + ni*16 + l15;
        C[row * (long)Nfull + col] = f2bf(acc[mi][ni][r] * cscale);
      }
}

// ---------------- h[16*1024,256] -> hT[16*256,1024] (bf16 transpose) -------------------
__global__ __launch_bounds__(256) void transpose_h(const short* __restrict__ h,
                                                   short* __restrict__ hT) {
  __shared__ short t[64][72];
  const int k0 = blockIdx.x * 64, n0 = blockIdx.y * 64, b = blockIdx.z;
  const int tid = threadIdx.x;
  {
    int row = tid >> 2, cch = (tid & 3) * 16;
    const short* src = h + ((long)b*1024 + k0 + row) * 256 + n0 + cch;
    *(bf16x8*)&t[row][cch]     = *(const bf16x8*)src;
    *(bf16x8*)&t[row][cch + 8] = *(const bf16x8*)(src + 8);
  }
  __syncthreads();
  {
    int n = tid >> 2, kch = (tid & 3) * 16;
    bf16x8 lo, hi;
    #pragma unroll
    for (int j = 0; j < 8; ++j) { lo[j] = t[kch + j][n]; hi[j] = t[kch + 8 + j][n]; }
    short* dst = hT + ((long)b*256 + n0 + n) * 1024 + k0 + kch;
    *(bf16x8*)dst       = lo;
    *(bf16x8*)(dst + 8) = hi;
  }
}

// ---------------- fused attention, 32x32x16 MFMA, QBLK=128, 4 waves, 2 blocks/CU -------
// Swapped QK^T: S = mfma(g, f) -> q=lane&31 lane-local (f pre-scaled by log2e -> raw
// exp2). P assembled IN-REGISTER via v_cvt_pk_bf16_f32 + v_permlane32_swap_b32.
// Swapped PV: y = mfma(hT, P). Counted s_waitcnt vmcnt(10) + raw barriers.
// Flat grid 512 with XCD swizzle: xcd=bid&7 owns batches {2*xcd, 2*xcd+1} -> K/V L2-local.
// Epilogue: normalize, per-wave LDS round-trip -> coalesced y stores.
__global__ __launch_bounds__(256, 2) void attn_kernel(const short* __restrict__ f,
    const short* __restrict__ g, const short* __restrict__ hT,
    short* __restrict__ y) {
  extern __shared__ __align__(16) char smem[];
  const int bid = blockIdx.x;
  const int xcd = bid & 7, idx = bid >> 3;
  const int b = xcd*2 + (idx >> 5);
  const int q0 = (idx & 31) * 128;
  const int tid = threadIdx.x, w = tid >> 6, lane = tid & 63;
  const int l31 = lane & 31, hi = lane >> 5;

  bf16x8 fq[4];
  {
    const short* frow = f + ((long)b*4096 + q0 + w*32 + l31) * 64;
    #pragma unroll
    for (int ks = 0; ks < 4; ++ks) fq[ks] = *(const bf16x8*)(frow + ks*16 + hi*8);
  }

  f32x16 acc2[8] = {};     // [nc2] : n = nc2*32 + (g&3)+8*(g>>2)+4*hi, q = l31
  float rsq = 0.f;

  auto stage = [&](int buf, int kt) {   // 10 gload16 per wave per call
    const int k0 = kt * 64;
    short* gbuf = (short*)(smem + buf*8192);
    short* hbuf = (short*)(smem + 16384 + buf*32768);
    #pragma unroll
    for (int it = 0; it < 2; ++it) {          // g: 64 rows x 8 slots = 512 chunks
      int c = it*256 + w*64 + lane;
      int row = c >> 3, gslot = (c & 7) ^ (row & 7);
      gload16(g + ((long)b*1024 + k0 + row)*64 + gslot*8, gbuf + (it*256 + w*64)*8);
    }
    #pragma unroll
    for (int it = 0; it < 8; ++it) {          // hT: 256 rows x 8 slots = 2048 chunks
      int c = it*256 + w*64 + lane;
      int row = c >> 3, gslot = (c & 7) ^ (row & 7);
      gload16(hT + ((long)b*256 + row)*1024 + k0 + gslot*8, hbuf + (it*256 + w*64)*8);
    }
  };

  stage(0, 0);
  int cur = 0;
  for (int kt = 0; kt < 16; ++kt) {
    if (kt < 15) {
      stage(cur ^ 1, kt + 1);
      // wait only for CURRENT tile's 10 loads (issued last iter); next's 10 stay in flight
      asm volatile("s_waitcnt vmcnt(10)" ::: "memory");
    } else {
      asm volatile("s_waitcnt vmcnt(0)" ::: "memory");
    }
    __builtin_amdgcn_s_barrier();          // current buffer visible to all waves
    const char* gcur = (const char*)(smem + cur*8192);
    const char* hcur = (const char*)(smem + 16384 + cur*32768);
    // ---- QK^T (swapped) + exp2 + in-register P^T fragment assembly ----
    bf16x8 pa[4];
    #pragma unroll
    for (int kc2 = 0; kc2 < 2; ++kc2) {
      f32x16 s2 = {};
      #pragma unroll
      for (int ks = 0; ks < 4; ++ks) {
        int key = kc2*32 + l31;
        bf16x8 gb = *(const bf16x8*)(gcur + key*128 + (((ks*2 + hi) ^ (l31 & 7)) << 4));
        s2 = mfma32(gb, fq[ks], s2);
      }
      #pragma unroll
      for (int fh = 0; fh < 2; ++fh) {
        const int G = fh*8;
        float e0 = exp2f(s2[G+0]), e1 = exp2f(s2[G+1]);
        float e2 = exp2f(s2[G+2]), e3 = exp2f(s2[G+3]);
        float e4 = exp2f(s2[G+4]), e5 = exp2f(s2[G+5]);
        float e6 = exp2f(s2[G+6]), e7 = exp2f(s2[G+7]);
        rsq += ((e0 + e1) + (e2 + e3)) + ((e4 + e5) + (e6 + e7));
        unsigned a0 = cvtpk(e0, e1), a1 = cvtpk(e2, e3);
        unsigned b0 = cvtpk(e4, e5), b1 = cvtpk(e6, e7);
        asm volatile("v_permlane32_swap_b32 %0, %1" : "+v"(b0), "+v"(a0));
        asm volatile("v_permlane32_swap_b32 %0, %1" : "+v"(b1), "+v"(a1));
        union { unsigned u[4]; bf16x8 v; } pk;
        pk.u[0] = a0; pk.u[1] = a1; pk.u[2] = b0; pk.u[3] = b1;
        pa[kc2*2 + fh] = pk.v;
      }
    }
    // ---- PV (swapped), P from registers ----
    __builtin_amdgcn_s_setprio(1);
    #pragma unroll
    for (int ks = 0; ks < 4; ++ks) {
      #pragma unroll
      for (int nc2 = 0; nc2 < 8; ++nc2) {
        int n = nc2*32 + l31;
        bf16x8 hb = *(const bf16x8*)(hcur + n*128 + (((ks*2 + hi) ^ (l31 & 7)) << 4));
        acc2[nc2] = mfma32(hb, pa[ks], acc2[nc2]);
      }
    }
    __builtin_amdgcn_s_setprio(0);
    __builtin_amdgcn_s_barrier();          // all waves done reading cur before overwrite
    cur ^= 1;
  }
  // ---- normalize + per-wave LDS round-trip -> coalesced y stores ----
  // After the final barrier all K/V buffers are dead; wave w uses smem + w*16KB as
  // [32 rows][32 slots of 16B] with slot XOR-swizzle d = s ^ row (4-way banks).
  rsq += __shfl_xor(rsq, 32);
  float ri = 1.f / rsq;
  short* yw = (short*)(smem + w*16384);
  #pragma unroll
  for (int nc2 = 0; nc2 < 8; ++nc2) {
    #pragma unroll
    for (int fh = 0; fh < 2; ++fh) {
      const int G = fh*8;
      unsigned a0 = cvtpk(acc2[nc2][G+0]*ri, acc2[nc2][G+1]*ri);
      unsigned a1 = cvtpk(acc2[nc2][G+2]*ri, acc2[nc2][G+3]*ri);
      unsigned b0 = cvtpk(acc2[nc2][G+4]*ri, acc2[nc2][G+5]*ri);
      unsigned b1 = cvtpk(acc2[nc2][G+6]*ri, acc2[nc2][G+7]*ri);
      asm volatile("v_permlane32_swap_b32 %0, %1" : "+v"(b0), "+v"(a0));
      asm volatile("v_permlane32_swap_b32 %0, %1" : "+v"(b1), "+v"(a1));
      union { unsigned u[4]; bf16x8 v; } pk;
      pk.u[0] = a0; pk.u[1] = a1; pk.u[2] = b0; pk.u[3] = b1;
      int s = (nc2*2 + fh)*2 + hi;                       // logical 16B slot 0..31
      *(bf16x8*)(yw + l31*256 + ((s ^ l31) * 8)) = pk.v; // row=l31 (q), swizzled slot
    }
  }
  // same-wave readback (compiler inserts lgkmcnt); linear LDS -> permuted-in-row global
  const long qb = (long)b*4096 + q0 + w*32;
  #pragma unroll
  for (int i = 0; i < 16; ++i) {
    int row = i*2 + hi;
    int s = l31 ^ row;                                   // logical slot at LDS pos l31
    bf16x8 v = *(const bf16x8*)(yw + row*256 + l31*8);
    *(bf16x8*)(y + (qb + row)*256 + s*8) = v;
  }
}

// ---------------- out = y[65536,256] @ WoT[512,256]^T + x (f32 out), streaming ---------
// UN-swapped orientation: A = y rows (from LDS, staged once), B = WoT cols (L2-resident),
// C/D col = lane&31 -> x-loads and out-stores are contiguous 128B segments. A-fragments
// (64 VGPR) loaded once per wave and reused across all 16 col-chunks. One barrier total.
__global__ __launch_bounds__(256) void gemm_out(const short* __restrict__ y,
    const short* __restrict__ WoT, const float* __restrict__ x,
    float* __restrict__ out) {
  __shared__ short ys[128*256];   // 64 KB, row-major with 16B-slot XOR swizzle
  const int q0 = blockIdx.x * 128;
  const int tid = threadIdx.x, w = tid >> 6, lane = tid & 63;
  const int l31 = lane & 31, hi = lane >> 5;
  #pragma unroll
  for (int it = 0; it < 16; ++it) {
    int c = it*256 + tid;
    int row = c >> 5, gslot = (c & 31) ^ (row & 31);
    gload16(y + ((long)q0 + row)*256 + gslot*8, ys + c*8);
  }
  asm volatile("s_waitcnt vmcnt(0)" ::: "memory");
  __builtin_amdgcn_s_barrier();
  // A-frags: wave w owns rows w*32..w*32+31; lane row = qr, k = kk*16 + hi*8 + j
  const int qr = w*32 + l31;
  bf16x8 ya[16];
  #pragma unroll
  for (int kk = 0; kk < 16; ++kk) {
    int s = kk*2 + hi;
    ya[kk] = *(const bf16x8*)(ys + qr*256 + ((s ^ (qr & 31)) * 8));
  }
  const long obase = (long)q0 * 512;
  for (int it = 0; it < 16; ++it) {
    const int c0 = it * 32;
    bf16x8 bw[16];
    const short* wrow = WoT + ((long)(c0 + l31))*256 + hi*8;
    #pragma unroll
    for (int ns = 0; ns < 16; ++ns) bw[ns] = *(const bf16x8*)(wrow + ns*16);
    float xv[16];
    #pragma unroll
    for (int r = 0; r < 16; ++r) {
      int rowoff = (r&3) + 8*(r>>2) + 4*hi;
      xv[r] = x[obase + (long)(w*32 + rowoff)*512 + c0 + l31];
    }
    f32x16 ao0 = {}, ao1 = {};
    #pragma unroll
    for (int ns2 = 0; ns2 < 8; ++ns2) {
      ao0 = mfma32(ya[2*ns2  ], bw[2*ns2  ], ao0);
      ao1 = mfma32(ya[2*ns2+1], bw[2*ns2+1], ao1);
    }
    #pragma unroll
    for (int r = 0; r < 16; ++r) {
      int rowoff = (r&3) + 8*(r>>2) + 4*hi;
      out[obase + (long)(w*32 + rowoff)*512 + c0 + l31] = ao0[r] + ao1[r] + xv[r];
    }
  }
}

extern "C" void kernel_launch(void* const* d_in, const int* in_sizes, int n_in,
                              void* d_out, int out_size, void* d_ws, size_t ws_size,
                              hipStream_t stream) {
  const float* x  = (const float*)d_in[0];
  const float* Wf = (const float*)d_in[1];
  const float* Wg = (const float*)d_in[2];
  const float* Wh = (const float*)d_in[3];
  const float* Wo = (const float*)d_in[4];
  float* out = (float*)d_out;

  // workspace carve-up (bf16 elements)
  short* xp  = (short*)d_ws;                    // [16*1024, 512]
  short* fb  = xp  + (long)16*1024*512;         // [65536, 64]
  short* gb  = fb  + (long)65536*64;            // [16384, 64]
  short* hb  = gb  + (long)16384*64;            // [16384, 256]
  short* hTb = hb  + (long)16384*256;           // [16*256, 1024]
  short* yb  = hTb + (long)16*256*1024;         // [65536, 256]
  short* WfT = yb  + (long)65536*256;           // [64, 512]
  short* WgT = WfT + 64*512;
  short* WhT = WgT + 64*512;
  short* WoT = WhT + 256*512;

  hipFuncSetAttribute((const void*)attn_kernel,
                      hipFuncAttributeMaxDynamicSharedMemorySize, 81920);

  const float LOG2E = 1.44269504f;
  prep_weights<<<1536, 256, 0, stream>>>(Wf, Wg, Wh, Wo, WfT, WgT, WhT, WoT);
  gemm_k512<true , true ><<<dim3(512, 1), 256, 0, stream>>>((const void*)x,  WfT, fb, 64,  xp, LOG2E);
  gemm_k512<false, false><<<dim3(128, 1), 256, 0, stream>>>((const void*)xp, WgT, gb, 64,  nullptr, 1.0f);
  gemm_k512<false, false><<<dim3(128, 4), 256, 0, stream>>>((const void*)xp, WhT, hb, 256, nullptr, 1.0f);
  transpose_h <<<dim3(16, 4, 16), 256, 0, stream>>>(hb, hTb);
  attn_kernel <<<512, 256, 81920, stream>>>(fb, gb, hTb, yb);
  gemm_out    <<<512, 256, 0, stream>>>(yb, WoT, x, out);
}